// Round 6
// baseline (986.323 us; speedup 1.0000x reference)
//
#include <hip/hip_runtime.h>
#include <hip/hip_bf16.h>
#include <math.h>

// Problem dims (fixed by reference)
#define Bq   8
#define Nq   16384
#define Dq   256
#define Eq   8
#define HIDq 128
#define KSEL 4096          // tokens per expert = N*TOPK/E
#define TOKENS (Bq * Nq)   // 131072

// out = 0.7 * dispatch + 0.0375   (alpha = 0.3)
#define SCALEq 0.7f
#define FLOORq 0.0375f

// ws layout (bytes). content/dvals are stored TRANSPOSED: [b][e][n]
#define CONT_OFF 0u
#define DIST_OFF 4194304u          // 1,048,576 f32
#define SUM_OFF  8388608u          // 1 double
#define TAU_OFF  (8388608u + 256u) // 64 u32
#define CUT_OFF  (8388608u + 512u) // 64 i32

// kA geometry: 256 threads = 4 waves; 64 tokens/block; wave w owns j-slice
// [32w, 32w+32). 2048 blocks -> 8 waves/SIMD (vs 2 for 1-thread-per-token).
#define TOK_BLK 64
#define KT      32                 // k-tile staged in LDS
#define JW      32                 // j (hidden) columns per wave

// monotone map: float -> u32 such that float order == unsigned order
__device__ __forceinline__ unsigned key_of(float f) {
    unsigned u = __float_as_uint(f);
    return (u & 0x80000000u) ? ~u : (u | 0x80000000u);
}

// ---------------- kernel A: content logits + distances + fp64 dist-sum ----
__global__ __launch_bounds__(256, 4) void kA(
    const float* __restrict__ tokens, const float* __restrict__ xyz,
    const float* __restrict__ W1, const float* __restrict__ b1,
    const float* __restrict__ W2, const float* __restrict__ b2,
    const float* __restrict__ centers,
    float* __restrict__ content, float* __restrict__ dvals,
    double* __restrict__ sumd)
{
    __shared__ float stage[TOK_BLK][KT + 4];   // pad 36: min-cycle LDS pattern
    __shared__ float part[4][Eq][TOK_BLK];     // [wave][e][token] partial acc
    __shared__ double lsum[4];

    const int t    = threadIdx.x;
    const int wq   = t >> 6;                   // wave id = j-quarter
    const int tk   = t & 63;                   // lane = local token
    const int base = blockIdx.x * TOK_BLK;
    const int tok  = base + tk;
    const int b    = tok >> 14;
    const int n    = tok & (Nq - 1);

    const float x0 = xyz[(size_t)tok * 3 + 0];
    const float x1 = xyz[(size_t)tok * 3 + 1];
    const float x2 = xyz[(size_t)tok * 3 + 2];

    // distances: wave wq handles e in {2wq, 2wq+1}; exact ref f32 op order
    double local = 0.0;
    #pragma unroll
    for (int q = 0; q < 2; ++q) {
        const int e = 2 * wq + q;
        float dx = x0 - centers[e * 3 + 0];
        float dy = x1 - centers[e * 3 + 1];
        float dz = x2 - centers[e * 3 + 2];
        float s  = (dx * dx + dy * dy) + dz * dz;
        float dd = sqrtf(s);
        dvals[((size_t)b * Eq + e) * Nq + n] = dd;
        local += (double)dd;
    }
    #pragma unroll
    for (int off = 32; off > 0; off >>= 1)
        local += __shfl_down(local, off);
    if (tk == 0) lsum[wq] = local;

    // h slice init from b1 (wave-uniform -> s_load)
    float h[JW];
    #pragma unroll
    for (int j = 0; j < JW; ++j) h[j] = b1[wq * JW + j];

    // K loop: stage 64x32 token tile in LDS (coalesced), then FMA with
    // wave-uniform W1 slice. Per-(token,j) accumulation order == previous
    // passing kernel (k ascending).
    for (int kt = 0; kt < Dq / KT; ++kt) {
        const int k0 = kt * KT;
        __syncthreads();   // readers of previous tile done
        #pragma unroll
        for (int p = 0; p < 2; ++p) {
            const int idx = p * 256 + t;       // 0..511
            const int row = idx >> 3;          // 0..63
            const int col = idx & 7;           // 0..7 (float4 units)
            const float4 v = *reinterpret_cast<const float4*>(
                tokens + (size_t)(base + row) * Dq + k0 + col * 4);
            *reinterpret_cast<float4*>(&stage[row][col * 4]) = v;
        }
        __syncthreads();
        #pragma unroll
        for (int c = 0; c < KT / 4; ++c) {
            const float4 xv = *reinterpret_cast<const float4*>(&stage[tk][c * 4]);
            const float* __restrict__ w =
                W1 + (size_t)(k0 + c * 4) * HIDq + wq * JW;
            #pragma unroll
            for (int j = 0; j < JW; ++j) h[j] = fmaf(xv.x, w[j], h[j]);
            #pragma unroll
            for (int j = 0; j < JW; ++j) h[j] = fmaf(xv.y, w[HIDq + j], h[j]);
            #pragma unroll
            for (int j = 0; j < JW; ++j) h[j] = fmaf(xv.z, w[2 * HIDq + j], h[j]);
            #pragma unroll
            for (int j = 0; j < JW; ++j) h[j] = fmaf(xv.w, w[3 * HIDq + j], h[j]);
        }
    }
    {   // gate_input dims 256..258 are spatial_xyz
        const float* __restrict__ w = W1 + (size_t)Dq * HIDq + wq * JW;
        #pragma unroll
        for (int j = 0; j < JW; ++j) h[j] = fmaf(x0, w[j], h[j]);
        #pragma unroll
        for (int j = 0; j < JW; ++j) h[j] = fmaf(x1, w[HIDq + j], h[j]);
        #pragma unroll
        for (int j = 0; j < JW; ++j) h[j] = fmaf(x2, w[2 * HIDq + j], h[j]);
    }

    // exact GELU + partial second GEMM over this wave's 32 j's
    float pe[Eq];
    #pragma unroll
    for (int e = 0; e < Eq; ++e) pe[e] = 0.0f;
    #pragma unroll
    for (int j = 0; j < JW; ++j) {
        const float v = h[j];
        const float g = 0.5f * v * (1.0f + erff(v * 0.70710678118654752440f));
        #pragma unroll
        for (int e = 0; e < Eq; ++e)
            pe[e] = fmaf(g, W2[(wq * JW + j) * Eq + e], pe[e]);
    }
    #pragma unroll
    for (int e = 0; e < Eq; ++e)
        part[wq][e][tk] = pe[e];               // lanes->consec addr, no conflict
    __syncthreads();

    if (wq == 0) {
        #pragma unroll
        for (int e = 0; e < Eq; ++e) {
            float tot = b2[e] + part[0][e][tk] + part[1][e][tk]
                              + part[2][e][tk] + part[3][e][tk];
            content[((size_t)b * Eq + e) * Nq + n] = tot;
        }
        if (tk == 0)
            atomicAdd(sumd, lsum[0] + lsum[1] + lsum[2] + lsum[3]);
    }
}

// ---------------- kernel B: exact k-th-largest select per (b,e) ----------
// 1024 threads/block; keys recomputed from global (L2-resident slices).
__global__ __launch_bounds__(1024, 1) void kB(
    const float* __restrict__ content, const float* __restrict__ dvals,
    const double* __restrict__ sumd,
    unsigned* __restrict__ tau_out, int* __restrict__ cut_out)
{
    const int be = blockIdx.x;      // 0..63 == b*Eq + e
    const int t  = threadIdx.x;

    __shared__ unsigned hist[256];
    __shared__ unsigned sufa[256];
    __shared__ unsigned sc[2];
    __shared__ unsigned mcnt[1024];

    const float meanf = (float)(sumd[0] * (1.0 / (double)(Bq * Nq * Eq)));
    const float denom = meanf + 1e-6f;

    const float* __restrict__ ce = content + (size_t)be * Nq;
    const float* __restrict__ de = dvals   + (size_t)be * Nq;

    unsigned prefix = 0, mask = 0;
    int needed = KSEL;
    for (int pass = 0; pass < 4; ++pass) {
        const int shift = 24 - 8 * pass;
        if (t < 256) hist[t] = 0;
        __syncthreads();
        for (int i = t; i < Nq; i += 1024) {
            float aff = (-de[i]) / denom;       // identical expr everywhere
            float lg  = ce[i] + aff;
            unsigned kk = key_of(lg);
            if ((kk & mask) == prefix)
                atomicAdd(&hist[(kk >> shift) & 0xFFu], 1u);
        }
        __syncthreads();
        if (t < 256) sufa[t] = hist[t];
        __syncthreads();
        // suffix-sum: sufa[i] = count of keys with byte >= i
        for (int st = 1; st < 256; st <<= 1) {
            unsigned v = 0, a = 0;
            if (t < 256) {
                v = sufa[t];
                a = (t + st < 256) ? sufa[t + st] : 0u;
            }
            __syncthreads();
            if (t < 256) sufa[t] = v + a;
            __syncthreads();
        }
        if (t < 256) {
            unsigned mine = sufa[t];
            unsigned hi   = (t < 255) ? sufa[t + 1] : 0u;
            if (mine >= (unsigned)needed && hi < (unsigned)needed) {
                sc[0] = (unsigned)t;             // selected bucket byte
                sc[1] = (unsigned)needed - hi;   // remaining inside bucket
            }
        }
        __syncthreads();
        prefix |= sc[0] << shift;
        mask   |= 0xFFu << shift;
        needed  = (int)sc[1];
        __syncthreads();
    }

    // tie cutoff: index of the `needed`-th key == prefix, ascending index
    // (jax.lax.top_k breaks ties by lower index). Block-parallel:
    // per-thread contiguous 16-segment count -> prefix scan -> rescan.
    const int bi = t * 16;
    int mym = 0;
    for (int i = 0; i < 16; ++i) {
        float aff = (-de[bi + i]) / denom;
        float lg  = ce[bi + i] + aff;
        mym += (key_of(lg) == prefix);
    }
    mcnt[t] = (unsigned)mym;
    __syncthreads();
    for (int st = 1; st < 1024; st <<= 1) {
        unsigned v = mcnt[t];
        unsigned a = (t >= st) ? mcnt[t - st] : 0u;
        __syncthreads();
        mcnt[t] = v + a;
        __syncthreads();
    }
    const int incl = (int)mcnt[t];
    const int excl = incl - mym;
    if (excl < needed && incl >= needed) {   // exactly one thread
        int r2 = needed - excl, c = 0, cut = bi;
        for (int i = 0; i < 16; ++i) {
            float aff = (-de[bi + i]) / denom;
            float lg  = ce[bi + i] + aff;
            if (key_of(lg) == prefix) {
                if (++c == r2) { cut = bi + i; break; }
            }
        }
        tau_out[be] = prefix;
        cut_out[be] = cut;
    }
}

// ---------------- kernel C: write output --------------------------------
__global__ __launch_bounds__(256) void kC(
    const float* __restrict__ content, const float* __restrict__ dvals,
    const double* __restrict__ sumd,
    const unsigned* __restrict__ tau, const int* __restrict__ cut,
    float* __restrict__ out)
{
    const int idx = blockIdx.x * 256 + threadIdx.x;   // (b,n) flat
    const int b = idx >> 14;
    const int n = idx & (Nq - 1);

    const float meanf = (float)(sumd[0] * (1.0 / (double)(Bq * Nq * Eq)));
    const float denom = meanf + 1e-6f;

    #pragma unroll
    for (int e = 0; e < Eq; ++e) {
        const size_t bt = ((size_t)b * Eq + e) * Nq + n;  // transposed read
        float aff = (-dvals[bt]) / denom;
        float lg  = content[bt] + aff;             // identical expr to kB
        unsigned k  = key_of(lg);
        unsigned tk = tau[b * Eq + e];
        bool sel = (k > tk) || (k == tk && n <= cut[b * Eq + e]);
        float disp = sel ? (1.0f / (1.0f + expf(-lg))) : 0.0f;
        out[(size_t)idx * Eq + e] = fmaf(SCALEq, disp, FLOORq);
    }
}

extern "C" void kernel_launch(void* const* d_in, const int* in_sizes, int n_in,
                              void* d_out, int out_size, void* d_ws, size_t ws_size,
                              hipStream_t stream) {
    const float* tokens  = (const float*)d_in[0];
    const float* xyz     = (const float*)d_in[1];
    const float* W1      = (const float*)d_in[2];
    const float* b1      = (const float*)d_in[3];
    const float* W2      = (const float*)d_in[4];
    const float* b2      = (const float*)d_in[5];
    const float* centers = (const float*)d_in[6];
    // d_in[7] = t (unused by the reference computation)

    char* ws = (char*)d_ws;
    float*    content = (float*)(ws + CONT_OFF);
    float*    dvals   = (float*)(ws + DIST_OFF);
    double*   sumd    = (double*)(ws + SUM_OFF);
    unsigned* tau     = (unsigned*)(ws + TAU_OFF);
    int*      cutv    = (int*)(ws + CUT_OFF);

    hipMemsetAsync(sumd, 0, sizeof(double), stream);
    kA<<<TOKENS / TOK_BLK, 256, 0, stream>>>(tokens, xyz, W1, b1, W2, b2,
                                             centers, content, dvals, sumd);
    kB<<<Bq * Eq, 1024, 0, stream>>>(content, dvals, sumd, tau, cutv);
    kC<<<TOKENS / 256, 256, 0, stream>>>(content, dvals, sumd, tau, cutv,
                                         (float*)d_out);
}

// Round 7
// 344.521 us; speedup vs baseline: 2.8629x; 2.8629x over previous
//
#include <hip/hip_runtime.h>
#include <hip/hip_bf16.h>
#include <math.h>

// Problem dims (fixed by reference)
#define Bq   8
#define Nq   16384
#define Dq   256
#define Eq   8
#define HIDq 128
#define KSEL 4096          // tokens per expert = N*TOPK/E
#define TOKENS (Bq * Nq)   // 131072

// out = 0.7 * dispatch + 0.0375   (alpha = 0.3)
#define SCALEq 0.7f
#define FLOORq 0.0375f

// ws layout (bytes). content/dvals are stored TRANSPOSED: [b][e][n]
#define CONT_OFF 0u
#define DIST_OFF 4194304u          // 1,048,576 f32
#define SUM_OFF  8388608u          // 1 double
#define TAU_OFF  (8388608u + 256u) // 64 u32
#define CUT_OFF  (8388608u + 512u) // 64 i32

// kA geometry: 256 threads; 64 tokens/block; thread (jg=t>>4, tg=t&15)
// computes acc[4 tokens (tg+16i)][8 j (jg*8+jj)] — 32 VGPR accumulator,
// no big per-thread arrays (round-6 spilled to scratch: WRITE_SIZE 551MB).
#define TOK_BLK 64
#define KT      32

// monotone map: float -> u32 such that float order == unsigned order
__device__ __forceinline__ unsigned key_of(float f) {
    unsigned u = __float_as_uint(f);
    return (u & 0x80000000u) ? ~u : (u | 0x80000000u);
}

// ---------------- kernel A: content logits + distances + fp64 dist-sum ----
__global__ __launch_bounds__(256, 4) void kA(
    const float* __restrict__ tokens, const float* __restrict__ xyz,
    const float* __restrict__ W1, const float* __restrict__ b1,
    const float* __restrict__ W2, const float* __restrict__ b2,
    const float* __restrict__ centers,
    float* __restrict__ content, float* __restrict__ dvals,
    double* __restrict__ sumd)
{
    __shared__ float ltok[TOK_BLK][KT + 4];   // [64][36]: read = 2-way = free
    __shared__ float w1s[KT][HIDq + 4];       // [32][132]: row 528B, 16B-align
    __shared__ float sW2[HIDq * Eq];          // 4 KB
    __shared__ float sxyz[TOK_BLK * 3];
    __shared__ float pw[4][TOK_BLK][Eq + 1];  // pad 9: conflict-free final sum

    const int t    = threadIdx.x;
    const int w    = t >> 6;                  // wave id (jg quarter)
    const int jg   = t >> 4;                  // 0..15 -> j slice [8jg, 8jg+8)
    const int tg   = t & 15;                  // tokens tg + 16i
    const int base = blockIdx.x * TOK_BLK;

    // one-time stages
    *reinterpret_cast<float4*>(&sW2[t * 4]) =
        *reinterpret_cast<const float4*>(W2 + t * 4);           // 1024 floats
    if (t < TOK_BLK * 3) sxyz[t] = xyz[(size_t)base * 3 + t];

    // distances (threads 0..63, token base+t): exact ref f32 op order,
    // e ascending; one fp64 atomic per block.
    if (t < TOK_BLK) {
        const int token = base + t;
        const int bb = token >> 14, nn = token & (Nq - 1);
        const float x0 = xyz[(size_t)token * 3 + 0];
        const float x1 = xyz[(size_t)token * 3 + 1];
        const float x2 = xyz[(size_t)token * 3 + 2];
        double local = 0.0;
        #pragma unroll
        for (int e = 0; e < Eq; ++e) {
            float dx = x0 - centers[e * 3 + 0];
            float dy = x1 - centers[e * 3 + 1];
            float dz = x2 - centers[e * 3 + 2];
            float s  = (dx * dx + dy * dy) + dz * dz;
            float dd = sqrtf(s);
            dvals[((size_t)bb * Eq + e) * Nq + nn] = dd;
            local += (double)dd;
        }
        #pragma unroll
        for (int off = 32; off > 0; off >>= 1)
            local += __shfl_down(local, off);
        if (t == 0) atomicAdd(sumd, local);
    }

    // accumulators: init from b1 (bit-identical start to passing kernel)
    float acc[4][8];
    #pragma unroll
    for (int jj = 0; jj < 8; ++jj) {
        const float bv = b1[jg * 8 + jj];
        #pragma unroll
        for (int i = 0; i < 4; ++i) acc[i][jj] = bv;
    }

    // K loop: stage 64x32 token tile + 32x128 W1 chunk, rank-1 update.
    // Per-(token,j) accumulation order: k ascending — bit-identical to the
    // passing round-5 kernel.
    for (int kt = 0; kt < Dq / KT; ++kt) {
        __syncthreads();   // previous tile consumed (also covers sW2/sxyz)
        #pragma unroll
        for (int p = 0; p < 2; ++p) {
            const int f = p * 256 + t;
            const int row = f >> 3, col = f & 7;
            const float4 v = *reinterpret_cast<const float4*>(
                tokens + (size_t)(base + row) * Dq + kt * KT + col * 4);
            float2* dst = reinterpret_cast<float2*>(&ltok[row][col * 4]);
            dst[0] = make_float2(v.x, v.y);
            dst[1] = make_float2(v.z, v.w);
        }
        #pragma unroll
        for (int q = 0; q < 4; ++q) {
            const int f = q * 256 + t;
            const int kr = f >> 5, col = f & 31;
            *reinterpret_cast<float4*>(&w1s[kr][col * 4]) =
                *reinterpret_cast<const float4*>(
                    W1 + (size_t)(kt * KT + kr) * HIDq + col * 4);
        }
        __syncthreads();
        #pragma unroll 4
        for (int k = 0; k < KT; ++k) {
            const float a0 = ltok[tg][k];
            const float a1 = ltok[tg + 16][k];
            const float a2 = ltok[tg + 32][k];
            const float a3 = ltok[tg + 48][k];
            const float4 wv0 = *reinterpret_cast<const float4*>(&w1s[k][jg * 8]);
            const float4 wv1 = *reinterpret_cast<const float4*>(&w1s[k][jg * 8 + 4]);
            const float wj[8] = {wv0.x, wv0.y, wv0.z, wv0.w,
                                 wv1.x, wv1.y, wv1.z, wv1.w};
            #pragma unroll
            for (int jj = 0; jj < 8; ++jj) {
                acc[0][jj] = fmaf(a0, wj[jj], acc[0][jj]);
                acc[1][jj] = fmaf(a1, wj[jj], acc[1][jj]);
                acc[2][jj] = fmaf(a2, wj[jj], acc[2][jj]);
                acc[3][jj] = fmaf(a3, wj[jj], acc[3][jj]);
            }
        }
    }

    // gate_input dims 256..258 (xyz), order x0,x1,x2 — matches passing kernel
    {
        float xr[3][4];
        #pragma unroll
        for (int i = 0; i < 4; ++i) {
            xr[0][i] = sxyz[(tg + 16 * i) * 3 + 0];
            xr[1][i] = sxyz[(tg + 16 * i) * 3 + 1];
            xr[2][i] = sxyz[(tg + 16 * i) * 3 + 2];
        }
        #pragma unroll
        for (int c = 0; c < 3; ++c) {
            float wrow[8];
            #pragma unroll
            for (int jj = 0; jj < 8; ++jj)
                wrow[jj] = W1[(size_t)(Dq + c) * HIDq + jg * 8 + jj];
            #pragma unroll
            for (int jj = 0; jj < 8; ++jj) {
                acc[0][jj] = fmaf(xr[c][0], wrow[jj], acc[0][jj]);
                acc[1][jj] = fmaf(xr[c][1], wrow[jj], acc[1][jj]);
                acc[2][jj] = fmaf(xr[c][2], wrow[jj], acc[2][jj]);
                acc[3][jj] = fmaf(xr[c][3], wrow[jj], acc[3][jj]);
            }
        }
    }

    // exact GELU + per-thread partial MLP2 over this thread's 8 j's
    float pe[4][8];
    #pragma unroll
    for (int i = 0; i < 4; ++i)
        #pragma unroll
        for (int e = 0; e < Eq; ++e) pe[i][e] = 0.0f;
    #pragma unroll
    for (int jj = 0; jj < 8; ++jj) {
        float w2r[8];
        #pragma unroll
        for (int e = 0; e < Eq; ++e) w2r[e] = sW2[(jg * 8 + jj) * Eq + e];
        #pragma unroll
        for (int i = 0; i < 4; ++i) {
            const float v = acc[i][jj];
            const float g = 0.5f * v * (1.0f + erff(v * 0.70710678118654752440f));
            #pragma unroll
            for (int e = 0; e < Eq; ++e)
                pe[i][e] = fmaf(g, w2r[e], pe[i][e]);
        }
    }

    // reduce across the wave's 4 jg slices (xor-16 then xor-32: both lanes
    // of a pair compute a+b / b+a — commutative, so deterministic)
    #pragma unroll
    for (int i = 0; i < 4; ++i)
        #pragma unroll
        for (int e = 0; e < Eq; ++e) {
            float x = pe[i][e];
            x += __shfl_xor(x, 16);
            x += __shfl_xor(x, 32);
            pe[i][e] = x;
        }
    if ((t & 48) == 0) {   // one lane group per wave writes the wave partial
        #pragma unroll
        for (int i = 0; i < 4; ++i)
            #pragma unroll
            for (int e = 0; e < Eq; ++e)
                pw[w][tg + 16 * i][e] = pe[i][e];
    }
    __syncthreads();

    // final: b2 + wave partials in ascending wave order (fixed, deterministic)
    #pragma unroll
    for (int s = 0; s < 2; ++s) {
        const int id = s * 256 + t;
        const int e  = id >> 6;           // 0..7
        const int tl = id & 63;
        const int token = base + tl;
        const int bb = token >> 14, nn = token & (Nq - 1);
        float tot = b2[e] + pw[0][tl][e] + pw[1][tl][e]
                          + pw[2][tl][e] + pw[3][tl][e];
        content[((size_t)bb * Eq + e) * Nq + nn] = tot;
    }
}

// ---------------- kernel B: exact k-th-largest select per (b,e) ----------
// 1024 threads/block; keys recomputed from global (L2-resident slices).
__global__ __launch_bounds__(1024, 1) void kB(
    const float* __restrict__ content, const float* __restrict__ dvals,
    const double* __restrict__ sumd,
    unsigned* __restrict__ tau_out, int* __restrict__ cut_out)
{
    const int be = blockIdx.x;      // 0..63 == b*Eq + e
    const int t  = threadIdx.x;

    __shared__ unsigned hist[256];
    __shared__ unsigned sufa[256];
    __shared__ unsigned sc[2];
    __shared__ unsigned mcnt[1024];

    const float meanf = (float)(sumd[0] * (1.0 / (double)(Bq * Nq * Eq)));
    const float denom = meanf + 1e-6f;

    const float* __restrict__ ce = content + (size_t)be * Nq;
    const float* __restrict__ de = dvals   + (size_t)be * Nq;

    unsigned prefix = 0, mask = 0;
    int needed = KSEL;
    for (int pass = 0; pass < 4; ++pass) {
        const int shift = 24 - 8 * pass;
        if (t < 256) hist[t] = 0;
        __syncthreads();
        for (int i = t; i < Nq; i += 1024) {
            float aff = (-de[i]) / denom;       // identical expr everywhere
            float lg  = ce[i] + aff;
            unsigned kk = key_of(lg);
            if ((kk & mask) == prefix)
                atomicAdd(&hist[(kk >> shift) & 0xFFu], 1u);
        }
        __syncthreads();
        if (t < 256) sufa[t] = hist[t];
        __syncthreads();
        // suffix-sum: sufa[i] = count of keys with byte >= i
        for (int st = 1; st < 256; st <<= 1) {
            unsigned v = 0, a = 0;
            if (t < 256) {
                v = sufa[t];
                a = (t + st < 256) ? sufa[t + st] : 0u;
            }
            __syncthreads();
            if (t < 256) sufa[t] = v + a;
            __syncthreads();
        }
        if (t < 256) {
            unsigned mine = sufa[t];
            unsigned hi   = (t < 255) ? sufa[t + 1] : 0u;
            if (mine >= (unsigned)needed && hi < (unsigned)needed) {
                sc[0] = (unsigned)t;             // selected bucket byte
                sc[1] = (unsigned)needed - hi;   // remaining inside bucket
            }
        }
        __syncthreads();
        prefix |= sc[0] << shift;
        mask   |= 0xFFu << shift;
        needed  = (int)sc[1];
        __syncthreads();
    }

    // tie cutoff: index of the `needed`-th key == prefix, ascending index
    // (jax.lax.top_k breaks ties by lower index). Block-parallel:
    // per-thread contiguous 16-segment count -> prefix scan -> rescan.
    const int bi = t * 16;
    int mym = 0;
    for (int i = 0; i < 16; ++i) {
        float aff = (-de[bi + i]) / denom;
        float lg  = ce[bi + i] + aff;
        mym += (key_of(lg) == prefix);
    }
    mcnt[t] = (unsigned)mym;
    __syncthreads();
    for (int st = 1; st < 1024; st <<= 1) {
        unsigned v = mcnt[t];
        unsigned a = (t >= st) ? mcnt[t - st] : 0u;
        __syncthreads();
        mcnt[t] = v + a;
        __syncthreads();
    }
    const int incl = (int)mcnt[t];
    const int excl = incl - mym;
    if (excl < needed && incl >= needed) {   // exactly one thread
        int r2 = needed - excl, c = 0, cut = bi;
        for (int i = 0; i < 16; ++i) {
            float aff = (-de[bi + i]) / denom;
            float lg  = ce[bi + i] + aff;
            if (key_of(lg) == prefix) {
                if (++c == r2) { cut = bi + i; break; }
            }
        }
        tau_out[be] = prefix;
        cut_out[be] = cut;
    }
}

// ---------------- kernel C: write output --------------------------------
__global__ __launch_bounds__(256) void kC(
    const float* __restrict__ content, const float* __restrict__ dvals,
    const double* __restrict__ sumd,
    const unsigned* __restrict__ tau, const int* __restrict__ cut,
    float* __restrict__ out)
{
    const int idx = blockIdx.x * 256 + threadIdx.x;   // (b,n) flat
    const int b = idx >> 14;
    const int n = idx & (Nq - 1);

    const float meanf = (float)(sumd[0] * (1.0 / (double)(Bq * Nq * Eq)));
    const float denom = meanf + 1e-6f;

    #pragma unroll
    for (int e = 0; e < Eq; ++e) {
        const size_t bt = ((size_t)b * Eq + e) * Nq + n;  // transposed read
        float aff = (-dvals[bt]) / denom;
        float lg  = content[bt] + aff;             // identical expr to kB
        unsigned k  = key_of(lg);
        unsigned tk = tau[b * Eq + e];
        bool sel = (k > tk) || (k == tk && n <= cut[b * Eq + e]);
        float disp = sel ? (1.0f / (1.0f + expf(-lg))) : 0.0f;
        out[(size_t)idx * Eq + e] = fmaf(SCALEq, disp, FLOORq);
    }
}

extern "C" void kernel_launch(void* const* d_in, const int* in_sizes, int n_in,
                              void* d_out, int out_size, void* d_ws, size_t ws_size,
                              hipStream_t stream) {
    const float* tokens  = (const float*)d_in[0];
    const float* xyz     = (const float*)d_in[1];
    const float* W1      = (const float*)d_in[2];
    const float* b1      = (const float*)d_in[3];
    const float* W2      = (const float*)d_in[4];
    const float* b2      = (const float*)d_in[5];
    const float* centers = (const float*)d_in[6];
    // d_in[7] = t (unused by the reference computation)

    char* ws = (char*)d_ws;
    float*    content = (float*)(ws + CONT_OFF);
    float*    dvals   = (float*)(ws + DIST_OFF);
    double*   sumd    = (double*)(ws + SUM_OFF);
    unsigned* tau     = (unsigned*)(ws + TAU_OFF);
    int*      cutv    = (int*)(ws + CUT_OFF);

    hipMemsetAsync(sumd, 0, sizeof(double), stream);
    kA<<<TOKENS / TOK_BLK, 256, 0, stream>>>(tokens, xyz, W1, b1, W2, b2,
                                             centers, content, dvals, sumd);
    kB<<<Bq * Eq, 1024, 0, stream>>>(content, dvals, sumd, tau, cutv);
    kC<<<TOKENS / 256, 256, 0, stream>>>(content, dvals, sumd, tau, cutv,
                                         (float*)d_out);
}

// Round 8
// 322.709 us; speedup vs baseline: 3.0564x; 1.0676x over previous
//
#include <hip/hip_runtime.h>
#include <hip/hip_bf16.h>
#include <math.h>

// Problem dims (fixed by reference)
#define Bq   8
#define Nq   16384
#define Dq   256
#define Eq   8
#define HIDq 128
#define KSEL 4096          // tokens per expert = N*TOPK/E
#define TOKENS (Bq * Nq)   // 131072

// out = 0.7 * dispatch + 0.0375   (alpha = 0.3)
#define SCALEq 0.7f
#define FLOORq 0.0375f

// ws layout (bytes). content/dvals are stored TRANSPOSED: [b][e][n]
#define CONT_OFF 0u
#define DIST_OFF 4194304u          // 1,048,576 f32
#define SUM_OFF  8388608u          // 1 double
#define TAU_OFF  (8388608u + 256u) // 64 u32
#define CUT_OFF  (8388608u + 512u) // 64 i32

#define TOK_BLK 64
#define KT      32

// monotone map: float -> u32 such that float order == unsigned order
__device__ __forceinline__ unsigned key_of(float f) {
    unsigned u = __float_as_uint(f);
    return (u & 0x80000000u) ? ~u : (u | 0x80000000u);
}

// ---------------- kernel A: content logits + distances + fp64 dist-sum ----
// 256 thr / 64 tokens; thread (jg,tg) owns acc[4 tok][8 j]. LDS ~31KB
// (pw unioned over ltok) -> 5 blocks/CU ceiling; next-tile regs prefetched
// under compute (T14).
__global__ __launch_bounds__(256, 4) void kA(
    const float* __restrict__ tokens, const float* __restrict__ xyz,
    const float* __restrict__ W1, const float* __restrict__ b1,
    const float* __restrict__ W2, const float* __restrict__ b2,
    const float* __restrict__ centers,
    float* __restrict__ content, float* __restrict__ dvals,
    double* __restrict__ sumd)
{
    __shared__ float w1s[KT][HIDq + 4];              // 16896 B
    __shared__ __align__(16) float uni[TOK_BLK * (KT + 4)];  // 9216 B
    __shared__ float sW2[HIDq * Eq];                 // 4096 B
    __shared__ float sxyz[TOK_BLK * 3];              // 768 B

    float (*ltok)[KT + 4] = reinterpret_cast<float (*)[KT + 4]>(uni);
    float (*pw)[TOK_BLK][Eq + 1] =
        reinterpret_cast<float (*)[TOK_BLK][Eq + 1]>(uni);  // 2304 floats, ==ltok

    const int t    = threadIdx.x;
    const int w    = t >> 6;
    const int jg   = t >> 4;                 // 0..15 -> j slice [8jg, 8jg+8)
    const int tg   = t & 15;                 // tokens tg + 16i
    const int base = blockIdx.x * TOK_BLK;

    const int trow = t >> 3, tcol = t & 7;   // token-stage row/col (p adds 32)
    const int wrow = t >> 5, wcol = t & 31;  // W1-stage row base/col (q adds 8)

    // prefetch tile kt=0 into regs (completes under distance section)
    float4 t0 = *reinterpret_cast<const float4*>(
        tokens + (size_t)(base + trow) * Dq + tcol * 4);
    float4 t1 = *reinterpret_cast<const float4*>(
        tokens + (size_t)(base + 32 + trow) * Dq + tcol * 4);
    float4 w0 = *reinterpret_cast<const float4*>(
        W1 + (size_t)(wrow) * HIDq + wcol * 4);
    float4 w1v = *reinterpret_cast<const float4*>(
        W1 + (size_t)(8 + wrow) * HIDq + wcol * 4);
    float4 w2v = *reinterpret_cast<const float4*>(
        W1 + (size_t)(16 + wrow) * HIDq + wcol * 4);
    float4 w3v = *reinterpret_cast<const float4*>(
        W1 + (size_t)(24 + wrow) * HIDq + wcol * 4);

    // one-time LDS stages
    *reinterpret_cast<float4*>(&sW2[t * 4]) =
        *reinterpret_cast<const float4*>(W2 + t * 4);
    if (t < TOK_BLK * 3) sxyz[t] = xyz[(size_t)base * 3 + t];

    // distances (threads 0..63): exact ref f32 op order, e ascending
    if (t < TOK_BLK) {
        const int token = base + t;
        const int bb = token >> 14, nn = token & (Nq - 1);
        const float x0 = xyz[(size_t)token * 3 + 0];
        const float x1 = xyz[(size_t)token * 3 + 1];
        const float x2 = xyz[(size_t)token * 3 + 2];
        double local = 0.0;
        #pragma unroll
        for (int e = 0; e < Eq; ++e) {
            float dx = x0 - centers[e * 3 + 0];
            float dy = x1 - centers[e * 3 + 1];
            float dz = x2 - centers[e * 3 + 2];
            float s  = (dx * dx + dy * dy) + dz * dz;
            float dd = sqrtf(s);
            dvals[((size_t)bb * Eq + e) * Nq + nn] = dd;
            local += (double)dd;
        }
        #pragma unroll
        for (int off = 32; off > 0; off >>= 1)
            local += __shfl_down(local, off);
        if (t == 0) atomicAdd(sumd, local);
    }

    // accumulators: init from b1 (bit-identical start to passing kernels)
    float acc[4][8];
    #pragma unroll
    for (int jj = 0; jj < 8; ++jj) {
        const float bv = b1[jg * 8 + jj];
        #pragma unroll
        for (int i = 0; i < 4; ++i) acc[i][jj] = bv;
    }

    // K loop: ds_write staged regs -> barrier -> issue next-tile loads
    // (overlap with compute) -> compute. Accumulation order: k ascending,
    // bit-identical to round-5/7 passing kernels.
    for (int kt = 0; kt < Dq / KT; ++kt) {
        __syncthreads();   // prev tile consumed (covers one-time stages too)
        *reinterpret_cast<float4*>(&ltok[trow][tcol * 4])      = t0;
        *reinterpret_cast<float4*>(&ltok[32 + trow][tcol * 4]) = t1;
        *reinterpret_cast<float4*>(&w1s[wrow][wcol * 4])       = w0;
        *reinterpret_cast<float4*>(&w1s[8 + wrow][wcol * 4])   = w1v;
        *reinterpret_cast<float4*>(&w1s[16 + wrow][wcol * 4])  = w2v;
        *reinterpret_cast<float4*>(&w1s[24 + wrow][wcol * 4])  = w3v;
        __syncthreads();   // tile ready
        if (kt < Dq / KT - 1) {
            const int k0 = (kt + 1) * KT;
            t0 = *reinterpret_cast<const float4*>(
                tokens + (size_t)(base + trow) * Dq + k0 + tcol * 4);
            t1 = *reinterpret_cast<const float4*>(
                tokens + (size_t)(base + 32 + trow) * Dq + k0 + tcol * 4);
            w0 = *reinterpret_cast<const float4*>(
                W1 + (size_t)(k0 + wrow) * HIDq + wcol * 4);
            w1v = *reinterpret_cast<const float4*>(
                W1 + (size_t)(k0 + 8 + wrow) * HIDq + wcol * 4);
            w2v = *reinterpret_cast<const float4*>(
                W1 + (size_t)(k0 + 16 + wrow) * HIDq + wcol * 4);
            w3v = *reinterpret_cast<const float4*>(
                W1 + (size_t)(k0 + 24 + wrow) * HIDq + wcol * 4);
        }
        #pragma unroll 4
        for (int k = 0; k < KT; ++k) {
            const float a0 = ltok[tg][k];
            const float a1 = ltok[tg + 16][k];
            const float a2 = ltok[tg + 32][k];
            const float a3 = ltok[tg + 48][k];
            const float4 wv0 = *reinterpret_cast<const float4*>(&w1s[k][jg * 8]);
            const float4 wv1 = *reinterpret_cast<const float4*>(&w1s[k][jg * 8 + 4]);
            const float wj[8] = {wv0.x, wv0.y, wv0.z, wv0.w,
                                 wv1.x, wv1.y, wv1.z, wv1.w};
            #pragma unroll
            for (int jj = 0; jj < 8; ++jj) {
                acc[0][jj] = fmaf(a0, wj[jj], acc[0][jj]);
                acc[1][jj] = fmaf(a1, wj[jj], acc[1][jj]);
                acc[2][jj] = fmaf(a2, wj[jj], acc[2][jj]);
                acc[3][jj] = fmaf(a3, wj[jj], acc[3][jj]);
            }
        }
    }

    // gate_input dims 256..258 (xyz), order x0,x1,x2 — matches passing kernel
    {
        float xr[3][4];
        #pragma unroll
        for (int i = 0; i < 4; ++i) {
            xr[0][i] = sxyz[(tg + 16 * i) * 3 + 0];
            xr[1][i] = sxyz[(tg + 16 * i) * 3 + 1];
            xr[2][i] = sxyz[(tg + 16 * i) * 3 + 2];
        }
        #pragma unroll
        for (int c = 0; c < 3; ++c) {
            float wrow8[8];
            #pragma unroll
            for (int jj = 0; jj < 8; ++jj)
                wrow8[jj] = W1[(size_t)(Dq + c) * HIDq + jg * 8 + jj];
            #pragma unroll
            for (int jj = 0; jj < 8; ++jj) {
                acc[0][jj] = fmaf(xr[c][0], wrow8[jj], acc[0][jj]);
                acc[1][jj] = fmaf(xr[c][1], wrow8[jj], acc[1][jj]);
                acc[2][jj] = fmaf(xr[c][2], wrow8[jj], acc[2][jj]);
                acc[3][jj] = fmaf(xr[c][3], wrow8[jj], acc[3][jj]);
            }
        }
    }

    // exact GELU + per-thread partial MLP2 over this thread's 8 j's
    float pe[4][8];
    #pragma unroll
    for (int i = 0; i < 4; ++i)
        #pragma unroll
        for (int e = 0; e < Eq; ++e) pe[i][e] = 0.0f;
    #pragma unroll
    for (int jj = 0; jj < 8; ++jj) {
        float w2r[8];
        #pragma unroll
        for (int e = 0; e < Eq; ++e) w2r[e] = sW2[(jg * 8 + jj) * Eq + e];
        #pragma unroll
        for (int i = 0; i < 4; ++i) {
            const float v = acc[i][jj];
            const float g = 0.5f * v * (1.0f + erff(v * 0.70710678118654752440f));
            #pragma unroll
            for (int e = 0; e < Eq; ++e)
                pe[i][e] = fmaf(g, w2r[e], pe[i][e]);
        }
    }

    // reduce across the wave's 4 jg slices (commutative pairs: deterministic)
    #pragma unroll
    for (int i = 0; i < 4; ++i)
        #pragma unroll
        for (int e = 0; e < Eq; ++e) {
            float x = pe[i][e];
            x += __shfl_xor(x, 16);
            x += __shfl_xor(x, 32);
            pe[i][e] = x;
        }

    __syncthreads();   // ALL waves past last ltok read before pw (alias) write
    if ((t & 48) == 0) {
        #pragma unroll
        for (int i = 0; i < 4; ++i)
            #pragma unroll
            for (int e = 0; e < Eq; ++e)
                pw[w][tg + 16 * i][e] = pe[i][e];
    }
    __syncthreads();

    // final: b2 + wave partials in ascending wave order (fixed, deterministic)
    #pragma unroll
    for (int s = 0; s < 2; ++s) {
        const int id = s * 256 + t;
        const int e  = id >> 6;
        const int tl = id & 63;
        const int token = base + tl;
        const int bb = token >> 14, nn = token & (Nq - 1);
        float tot = b2[e] + pw[0][tl][e] + pw[1][tl][e]
                          + pw[2][tl][e] + pw[3][tl][e];
        content[((size_t)bb * Eq + e) * Nq + nn] = tot;
    }
}

// ---------------- kernel B: exact k-th-largest select per (b,e) ----------
// Keys computed ONCE into registers (16/thread, contiguous segment).
// 4 radix passes filter regs; 256-bin suffix-scan by wave 0 via shfl
// (no barriers); ~14 barriers total vs ~100 in round 7.
__global__ __launch_bounds__(1024, 1) void kB(
    const float* __restrict__ content, const float* __restrict__ dvals,
    const double* __restrict__ sumd,
    unsigned* __restrict__ tau_out, int* __restrict__ cut_out)
{
    const int be   = blockIdx.x;     // 0..63 == b*Eq + e
    const int t    = threadIdx.x;
    const int lane = t & 63, wv = t >> 6;

    __shared__ unsigned hist[256];
    __shared__ unsigned sc[2];
    __shared__ unsigned wsum[16];

    const float meanf = (float)(sumd[0] * (1.0 / (double)(Bq * Nq * Eq)));
    const float denom = meanf + 1e-6f;

    const float* __restrict__ ce = content + (size_t)be * Nq;
    const float* __restrict__ de = dvals   + (size_t)be * Nq;

    // compute this thread's 16 keys (global idx i0..i0+15), once
    const int i0 = t * 16;
    unsigned key[16];
    #pragma unroll
    for (int q = 0; q < 4; ++q) {
        const float4 c4 = *reinterpret_cast<const float4*>(ce + i0 + q * 4);
        const float4 d4 = *reinterpret_cast<const float4*>(de + i0 + q * 4);
        key[q * 4 + 0] = key_of(c4.x + (-d4.x) / denom);
        key[q * 4 + 1] = key_of(c4.y + (-d4.y) / denom);
        key[q * 4 + 2] = key_of(c4.z + (-d4.z) / denom);
        key[q * 4 + 3] = key_of(c4.w + (-d4.w) / denom);
    }

    unsigned prefix = 0, mask = 0;
    int needed = KSEL;
    #pragma unroll
    for (int pass = 0; pass < 4; ++pass) {
        const int shift = 24 - 8 * pass;
        if (t < 256) hist[t] = 0;
        __syncthreads();
        #pragma unroll
        for (int j = 0; j < 16; ++j)
            if ((key[j] & mask) == prefix)
                atomicAdd(&hist[(key[j] >> shift) & 0xFFu], 1u);
        __syncthreads();
        if (wv == 0) {
            // lane holds bins 4*lane .. 4*lane+3; lane-local suffix sums
            const unsigned h0 = hist[4 * lane + 0];
            const unsigned h1 = hist[4 * lane + 1];
            const unsigned h2 = hist[4 * lane + 2];
            const unsigned h3 = hist[4 * lane + 3];
            const unsigned s3 = h3, s2 = h2 + s3, s1 = h1 + s2, s0 = h0 + s1;
            // cross-lane suffix scan of lane totals (Hillis-Steele)
            unsigned tot = s0;
            #pragma unroll
            for (int off = 1; off < 64; off <<= 1) {
                unsigned u = __shfl_down(tot, off);
                if (lane + off < 64) tot += u;
            }
            unsigned totN = __shfl_down(tot, 1);
            if (lane == 63) totN = 0;
            const unsigned beyond = tot - s0;   // sum over lanes > lane
            const unsigned sufa0 = s0 + beyond, sufa1 = s1 + beyond,
                           sufa2 = s2 + beyond, sufa3 = s3 + beyond;
            const unsigned nd = (unsigned)needed;
            // exactly one (lane, i) satisfies sufa>=nd && next<nd
            if (sufa0 >= nd && sufa1 < nd) { sc[0] = 4u*lane + 0; sc[1] = nd - sufa1; }
            if (sufa1 >= nd && sufa2 < nd) { sc[0] = 4u*lane + 1; sc[1] = nd - sufa2; }
            if (sufa2 >= nd && sufa3 < nd) { sc[0] = 4u*lane + 2; sc[1] = nd - sufa3; }
            if (sufa3 >= nd && totN  < nd) { sc[0] = 4u*lane + 3; sc[1] = nd - totN;  }
        }
        __syncthreads();
        prefix |= sc[0] << shift;
        mask   |= 0xFFu << shift;
        needed  = (int)sc[1];
        __syncthreads();   // sc consumed before next pass's writes
    }

    // tie cutoff: needed-th smallest index with key == prefix
    // (jax.lax.top_k breaks ties by lower index)
    int mym = 0;
    #pragma unroll
    for (int j = 0; j < 16; ++j) mym += (key[j] == prefix);
    // inclusive prefix scan over 1024 threads (thread order == index order)
    unsigned v = (unsigned)mym;
    #pragma unroll
    for (int off = 1; off < 64; off <<= 1) {
        unsigned u = __shfl_up(v, off);
        if (lane >= off) v += u;
    }
    if (lane == 63) wsum[wv] = v;
    __syncthreads();
    unsigned woff = 0;
    for (int q2 = 0; q2 < wv; ++q2) woff += wsum[q2];
    const int incl = (int)(woff + v);
    const int excl = incl - mym;
    if (excl < needed && incl >= needed) {   // exactly one thread
        int r2 = needed - excl, c = 0, cut = i0;
        #pragma unroll
        for (int j = 0; j < 16; ++j) {
            if (key[j] == prefix) {
                if (++c == r2) { cut = i0 + j; }
            }
        }
        tau_out[be] = prefix;
        cut_out[be] = cut;
    }
}

// ---------------- kernel C: write output --------------------------------
__global__ __launch_bounds__(256) void kC(
    const float* __restrict__ content, const float* __restrict__ dvals,
    const double* __restrict__ sumd,
    const unsigned* __restrict__ tau, const int* __restrict__ cut,
    float* __restrict__ out)
{
    const int idx = blockIdx.x * 256 + threadIdx.x;   // (b,n) flat
    const int b = idx >> 14;
    const int n = idx & (Nq - 1);

    const float meanf = (float)(sumd[0] * (1.0 / (double)(Bq * Nq * Eq)));
    const float denom = meanf + 1e-6f;

    #pragma unroll
    for (int e = 0; e < Eq; ++e) {
        const size_t bt = ((size_t)b * Eq + e) * Nq + n;  // transposed read
        float aff = (-dvals[bt]) / denom;
        float lg  = content[bt] + aff;             // identical expr to kB
        unsigned k  = key_of(lg);
        unsigned tk = tau[b * Eq + e];
        bool sel = (k > tk) || (k == tk && n <= cut[b * Eq + e]);
        float disp = sel ? (1.0f / (1.0f + expf(-lg))) : 0.0f;
        out[(size_t)idx * Eq + e] = fmaf(SCALEq, disp, FLOORq);
    }
}

extern "C" void kernel_launch(void* const* d_in, const int* in_sizes, int n_in,
                              void* d_out, int out_size, void* d_ws, size_t ws_size,
                              hipStream_t stream) {
    const float* tokens  = (const float*)d_in[0];
    const float* xyz     = (const float*)d_in[1];
    const float* W1      = (const float*)d_in[2];
    const float* b1      = (const float*)d_in[3];
    const float* W2      = (const float*)d_in[4];
    const float* b2      = (const float*)d_in[5];
    const float* centers = (const float*)d_in[6];
    // d_in[7] = t (unused by the reference computation)

    char* ws = (char*)d_ws;
    float*    content = (float*)(ws + CONT_OFF);
    float*    dvals   = (float*)(ws + DIST_OFF);
    double*   sumd    = (double*)(ws + SUM_OFF);
    unsigned* tau     = (unsigned*)(ws + TAU_OFF);
    int*      cutv    = (int*)(ws + CUT_OFF);

    hipMemsetAsync(sumd, 0, sizeof(double), stream);
    kA<<<TOKENS / TOK_BLK, 256, 0, stream>>>(tokens, xyz, W1, b1, W2, b2,
                                             centers, content, dvals, sumd);
    kB<<<Bq * Eq, 1024, 0, stream>>>(content, dvals, sumd, tau, cutv);
    kC<<<TOKENS / 256, 256, 0, stream>>>(content, dvals, sumd, tau, cutv,
                                         (float*)d_out);
}